// Round 6
// baseline (454.487 us; speedup 1.0000x reference)
//
#include <hip/hip_runtime.h>
#include <hip/hip_bf16.h>

typedef __attribute__((ext_vector_type(8))) short s8;   // 8 bf16 = 4 VGPRs
typedef __attribute__((ext_vector_type(4))) float f4;

// gelu tanh-approx (JAX approximate=True), algebraically reduced:
// gelu(x) = x * (1 - 1/(exp(k)+1)),  k = x*(1.59576912 + 0.07135482 x^2)
__device__ __forceinline__ float gelu_fast(float x) {
    float x2 = x * x;
    float k  = x * fmaf(x2, 0.07135481624f, 1.59576912161f);
    float e  = __expf(k);
    float r  = __builtin_amdgcn_rcpf(e + 1.f);
    return x - x * r;
}

__device__ __forceinline__ short f2bf_bits(float v) {
    __hip_bfloat16 b = __float2bfloat16(v);
    return *(short*)&b;
}

struct RP { const int* edst; int E; int N; int* rowptr; };

// Build CSR row pointers for all 4 graphs (edst sorted ascending).
__global__ void rowptr4_kernel(RP a, RP b, RP c, RP d) {
    RP g = (blockIdx.y == 0) ? a : (blockIdx.y == 1) ? b : (blockIdx.y == 2) ? c : d;
    int i = blockIdx.x * blockDim.x + threadIdx.x;
    if (i >= g.E) return;
    int dd = g.edst[i];
    int p  = (i == 0) ? -1 : g.edst[i - 1];
    for (int r = p + 1; r <= dd; ++r) g.rowptr[r] = i;
    if (i == g.E - 1)
        for (int r = dd + 1; r <= g.N; ++r) g.rowptr[r] = g.E;
}

// Pack w2 (64x128 f32, row-major [k][ch]) into MFMA B-fragment order, bf16.
// group g = ((w*4+T)*2+s); lane holds 8 bf16: k = s*32+q*8+j, ch = 64w+4n+T
// (channel remap: tile T covers ch = 64w + 4n + T so f_y gathers are float4).
__global__ __launch_bounds__(128) void pack_w2_kernel(
    const float* __restrict__ wa, const float* __restrict__ wb,
    const float* __restrict__ wc, const float* __restrict__ wd,
    short* __restrict__ out)
{
    const float* w2 = (blockIdx.x == 0) ? wa : (blockIdx.x == 1) ? wb
                    : (blockIdx.x == 2) ? wc : wd;
    short* dst = out + (size_t)blockIdx.x * 8192;
    const int t = threadIdx.x;
    const int w = t >> 6, lane = t & 63, q = (lane >> 4), n = lane & 15;
#pragma unroll
    for (int T = 0; T < 4; ++T)
#pragma unroll
        for (int s = 0; s < 2; ++s)
#pragma unroll
            for (int j = 0; j < 8; ++j) {
                int k  = s * 32 + q * 8 + j;
                int ch = 64 * w + 4 * n + T;
                dst[((((w * 4 + T) * 2 + s) * 64) + lane) * 8 + j] =
                    f2bf_bits(w2[k * 128 + ch]);
            }
}

// Chunked gno: each block handles dst nodes [blockIdx.x*chunk, ...+chunk).
// Weights loaded once per block. 64-edge superstages staged one-ahead
// (software pipeline), double-buffered s_gb -> 1 barrier per 16-edge group.
__global__ __launch_bounds__(128) void gno_kernel(
    const float* __restrict__ coords, int n0, int sx, int sy,
    const float* __restrict__ f_y,
    const int* __restrict__ esrc, const int* __restrict__ rowptr,
    int N, int chunk,
    const float* __restrict__ w1, const float* __restrict__ b1,
    const short* __restrict__ w2bf, const float* __restrict__ b2,
    const float* __restrict__ add0, const float* __restrict__ add1,
    int do_relu, float* __restrict__ out,
    const float* __restrict__ projw, const float* __restrict__ projb,
    float* __restrict__ fout)
{
    const int t = threadIdx.x;
    const int w = t >> 6, lane = t & 63, q = lane >> 4, n = lane & 15;
    const int d0 = blockIdx.x * chunk;
    if (d0 >= N) return;
    const int d1 = min(d0 + chunk, N);

    __shared__ int   s_rp[8];
    __shared__ int   s_src[2][64];
    __shared__ float s_yx[2][64], s_yy[2][64];
    __shared__ __align__(16) short s_gb[2][16 * 72];
    __shared__ float s_pr[128];
    __shared__ float sred[6];

    if (t <= d1 - d0) s_rp[t] = rowptr[d0 + t];

    // per-block weight prologue (registers)
    const float rw0 = w1[lane], rw1 = w1[64 + lane];
    const float rwx = w1[128 + lane], rwy = w1[192 + lane], rb1 = b1[lane];
    s8 bfrag[4][2];
    const s8* w2f = (const s8*)w2bf;
#pragma unroll
    for (int T = 0; T < 4; ++T)
#pragma unroll
        for (int s = 0; s < 2; ++s)
            bfrag[T][s] = w2f[((w * 4 + T) * 2 + s) * 64 + lane];
    const f4 b2c = *(const f4*)&b2[w * 64 + 4 * n];

    __syncthreads();   // s_rp visible

    // staging iterator -> first non-empty dst
    int sd, sbase = 0, shi = 0;
    {
        int i = 0;
        while (d0 + i < d1 && s_rp[i] == s_rp[i + 1]) ++i;
        sd = d0 + i;
        if (sd < d1) { sbase = s_rp[i]; shi = s_rp[i + 1]; }
    }
    int cb = 0;
    if (sd < d1 && t < 64) {
        int e = sbase + t; if (e >= shi) e = shi - 1;
        int sv = esrc[e];
        s_src[0][t] = sv;
        s_yx[0][t]  = coords[(long)sv * sy];
        s_yy[0][t]  = coords[n0 + (long)sv * sy];
    }
    __syncthreads();   // initial stage visible

    int gbp = 0;
    float cxx = coords[(long)d0 * sx];
    float cxy = coords[n0 + (long)d0 * sx];

    for (int d = d0; d < d1; ++d) {
        float nxx = 0.f, nxy = 0.f;
        if (d + 1 < d1) {
            nxx = coords[(long)(d + 1) * sx];
            nxy = coords[n0 + (long)(d + 1) * sx];
        }
        const int lo = s_rp[d - d0], hi = s_rp[d - d0 + 1];
        const float xcc = fmaf(cxx, rwx, fmaf(cxy, rwy, rb1));
        f4 acc = {0.f, 0.f, 0.f, 0.f};

        for (int ss = lo; ss < hi; ss += 64) {
            // advance iterator; stage NEXT superstage into cb^1 (covered by
            // this superstage's compute; visibility via the group barriers)
            {
                int nsd = sd, nsbase = sbase + 64, nshi = shi;
                if (nsbase >= nshi) {
                    int i = nsd - d0 + 1;
                    while (d0 + i < d1 && s_rp[i] == s_rp[i + 1]) ++i;
                    nsd = d0 + i;
                    if (nsd < d1) { nsbase = s_rp[i]; nshi = s_rp[i + 1]; }
                }
                if (nsd < d1 && t < 64) {
                    int e = nsbase + t; if (e >= nshi) e = nshi - 1;
                    int sv = esrc[e];
                    s_src[cb ^ 1][t] = sv;
                    s_yx[cb ^ 1][t]  = coords[(long)sv * sy];
                    s_yy[cb ^ 1][t]  = coords[n0 + (long)sv * sy];
                }
                sd = nsd; sbase = nsbase; shi = nshi;
            }
            const int ssn = min(64, hi - ss);
            for (int goff = 0; goff < ssn; goff += 16) {
                const int cnt = min(16, ssn - goff);
                // f_y gather, float4 per C-row (channels 64w+4n+T)
                f4 fv[4];
#pragma unroll
                for (int r = 0; r < 4; ++r) {
                    int m = q * 4 + r;
                    if (m < cnt) {
                        long srow = (long)s_src[cb][goff + m] * 128;
                        fv[r] = *(const f4*)&f_y[srow + w * 64 + 4 * n];
                    } else {
                        f4 z = {0.f, 0.f, 0.f, 0.f};
                        fv[r] = z;
                    }
                }
                // layer1: edge j = 2*i + w (group-local), hidden = lane
#pragma unroll
                for (int i = 0; i < 8; ++i) {
                    int j = 2 * i + w;
                    int p = goff + j;
                    float x = fmaf(s_yx[cb][p], rw0, fmaf(s_yy[cb][p], rw1, xcc));
                    s_gb[gbp][j * 72 + lane] = f2bf_bits(gelu_fast(x));
                }
                __syncthreads();
                // layer2 MFMA: A m=edge (lane&15), k=q*8+j
                const s8 a0 = *(const s8*)&s_gb[gbp][n * 72 + q * 8];
                const s8 a1 = *(const s8*)&s_gb[gbp][n * 72 + q * 8 + 32];
                f4 c[4];
#pragma unroll
                for (int T = 0; T < 4; ++T) {
                    f4 z = {0.f, 0.f, 0.f, 0.f};
                    z = __builtin_amdgcn_mfma_f32_16x16x32_bf16(a0, bfrag[T][0], z, 0, 0, 0);
                    c[T] = __builtin_amdgcn_mfma_f32_16x16x32_bf16(a1, bfrag[T][1], z, 0, 0, 0);
                }
#pragma unroll
                for (int r = 0; r < 4; ++r)
#pragma unroll
                    for (int T = 0; T < 4; ++T)
                        acc[T] += (c[T][r] + b2c[T]) * fv[r][T];
                gbp ^= 1;
            }
            cb ^= 1;
        }

        // quad-reduce (edge-row partitions), epilogue
        const float inv = 1.f / fmaxf((float)(hi - lo), 1.f);
        f4 res;
#pragma unroll
        for (int T = 0; T < 4; ++T) {
            float v = acc[T];
            v += __shfl_xor(v, 16, 64);
            v += __shfl_xor(v, 32, 64);
            res[T] = v * inv;
        }
        const long obase = (long)d * 128 + w * 64 + 4 * n;
        if (!projw) {
            if (q == 0) {
                if (add0) res += *(const f4*)&add0[obase];
                if (add1) res += *(const f4*)&add1[obase];
                if (do_relu) {
#pragma unroll
                    for (int T = 0; T < 4; ++T) res[T] = fmaxf(res[T], 0.f);
                }
                *(f4*)&out[obase] = res;
            }
        } else {
            __syncthreads();
            if (q == 0) {
                if (add0) res += *(const f4*)&add0[obase];
                if (add1) res += *(const f4*)&add1[obase];
                if (do_relu) {
#pragma unroll
                    for (int T = 0; T < 4; ++T) res[T] = fmaxf(res[T], 0.f);
                }
                *(f4*)&s_pr[w * 64 + 4 * n] = res;
            }
            __syncthreads();
            float v = s_pr[t];
            float p0 = v * projw[t * 3 + 0];
            float p1 = v * projw[t * 3 + 1];
            float p2 = v * projw[t * 3 + 2];
#pragma unroll
            for (int o = 32; o > 0; o >>= 1) {
                p0 += __shfl_down(p0, o);
                p1 += __shfl_down(p1, o);
                p2 += __shfl_down(p2, o);
            }
            if (lane == 0) { sred[w * 3 + 0] = p0; sred[w * 3 + 1] = p1; sred[w * 3 + 2] = p2; }
            __syncthreads();
            if (t < 3) fout[d * 3 + t] = sred[t] + sred[3 + t] + projb[t];
        }
        cxx = nxx; cxy = nxy;
    }
}

// v_down1 = relu(base + addl); w1out[r,c] = bias[c] + sum_h v_down1[r,h]*W[h,c]
__global__ __launch_bounds__(128) void fused_relu_mm_kernel(
    const float* __restrict__ base, const float* __restrict__ addl,
    float* __restrict__ vout,
    const float* __restrict__ W, const float* __restrict__ bias,
    float* __restrict__ out, int R)
{
    const int r0 = blockIdx.x * 8;
    const int t = threadIdx.x;
    __shared__ float s_x[8 * 128];
#pragma unroll
    for (int j = 0; j < 8; ++j) {
        int r = r0 + j;
        if (r < R) {
            long o = (long)r * 128 + t;
            float v = base[o] + (addl ? addl[o] : 0.f);
            v = fmaxf(v, 0.f);
            s_x[j * 128 + t] = v;
            vout[o] = v;
        } else s_x[j * 128 + t] = 0.f;
    }
    __syncthreads();
    float acc[8];
    const float bc = bias[t];
#pragma unroll
    for (int j = 0; j < 8; ++j) acc[j] = bc;
    for (int hh = 0; hh < 128; ++hh) {
        float wv = W[hh * 128 + t];
#pragma unroll
        for (int j = 0; j < 8; ++j) acc[j] += s_x[j * 128 + hh] * wv;
    }
#pragma unroll
    for (int j = 0; j < 8; ++j) {
        int r = r0 + j;
        if (r < R) out[(long)r * 128 + t] = acc[j];
    }
}

// plain matmul (for W0 term): out = X @ W + bias
__global__ __launch_bounds__(128) void matmul128_kernel(
    const float* __restrict__ X, const float* __restrict__ W,
    const float* __restrict__ bias, float* __restrict__ out, int R)
{
    const int r0 = blockIdx.x * 8;
    const int t = threadIdx.x;
    __shared__ float s_x[8 * 128];
#pragma unroll
    for (int j = 0; j < 8; ++j) {
        int r = r0 + j;
        s_x[j * 128 + t] = (r < R) ? X[(long)r * 128 + t] : 0.f;
    }
    __syncthreads();
    float acc[8];
    const float bc = bias[t];
#pragma unroll
    for (int j = 0; j < 8; ++j) acc[j] = bc;
    for (int hh = 0; hh < 128; ++hh) {
        float wv = W[hh * 128 + t];
#pragma unroll
        for (int j = 0; j < 8; ++j) acc[j] += s_x[j * 128 + hh] * wv;
    }
#pragma unroll
    for (int j = 0; j < 8; ++j) {
        int r = r0 + j;
        if (r < R) out[(long)r * 128 + t] = acc[j];
    }
}

// v_down0 = samples @ lift_w + lift_b ; one block per node, 128 threads
__global__ __launch_bounds__(128) void lift_kernel(
    const float* __restrict__ samples, const float* __restrict__ W,
    const float* __restrict__ bias, float* __restrict__ out, int N)
{
    const int i = blockIdx.x;
    const int t = threadIdx.x;
    float s0 = samples[i * 3 + 0];
    float s1 = samples[i * 3 + 1];
    float s2 = samples[i * 3 + 2];
    out[(long)i * 128 + t] = s0 * W[t] + s1 * W[128 + t] + s2 * W[256 + t] + bias[t];
}

extern "C" void kernel_launch(void* const* d_in, const int* in_sizes, int n_in,
                              void* d_out, int out_size, void* d_ws, size_t ws_size,
                              hipStream_t stream)
{
    const float* coords  = (const float*)d_in[0];
    const float* samples = (const float*)d_in[1];
    // d_in[2] = sigma (unused)
    const float* lift_w  = (const float*)d_in[3];
    const float* lift_b  = (const float*)d_in[4];
    const float* proj_w  = (const float*)d_in[5];
    const float* proj_b  = (const float*)d_in[6];
    const float* W0_w    = (const float*)d_in[7];
    const float* W0_b    = (const float*)d_in[8];
    const float* W1_w    = (const float*)d_in[9];
    const float* W1_b    = (const float*)d_in[10];
    const float *gw1[4], *gb1[4], *gw2[4], *gb2[4];   // 0=gk00,1=gk01,2=gk10,3=gk11
    for (int g = 0; g < 4; ++g) {
        gw1[g] = (const float*)d_in[11 + 4 * g + 0];
        gb1[g] = (const float*)d_in[11 + 4 * g + 1];
        gw2[g] = (const float*)d_in[11 + 4 * g + 2];
        gb2[g] = (const float*)d_in[11 + 4 * g + 3];
    }
    const int* es[4]; const int* ed[4]; int E[4];
    for (int g = 0; g < 4; ++g) {
        es[g] = (const int*)d_in[27 + 2 * g];
        ed[g] = (const int*)d_in[27 + 2 * g + 1];
        E[g]  = in_sizes[27 + 2 * g];
    }

    const int N0 = in_sizes[0] / 2;     // 8192
    const int N1 = (N0 + 1) / 2;        // 4096

    float* ws = (float*)d_ws;
    float* v_down0 = ws;                              // N0*128
    float* w0term  = v_down0 + (size_t)N0 * 128;      // N0*128
    float* gno00o  = w0term  + (size_t)N0 * 128;      // N0*128
    float* gno01b  = gno00o  + (size_t)N0 * 128;      // N1*128
    float* v_down1 = gno01b  + (size_t)N1 * 128;      // N1*128
    float* w1term  = v_down1 + (size_t)N1 * 128;      // N1*128
    float* v_up1   = w1term  + (size_t)N1 * 128;      // N1*128
    short* w2pack  = (short*)(v_up1 + (size_t)N1 * 128);  // 4*8192 bf16
    int*   rp      = (int*)(w2pack + 4 * 8192);
    int* rp00 = rp;                // N0+1
    int* rp01 = rp00 + (N0 + 1);   // N1+1
    int* rp10 = rp01 + (N1 + 1);   // N0+1
    int* rp11 = rp10 + (N0 + 1);   // N1+1

    // CSR row pointers for all 4 graphs
    {
        int maxE = E[0];
        for (int g = 1; g < 4; ++g) maxE = max(maxE, E[g]);
        RP a = {ed[0], E[0], N0, rp00};
        RP b = {ed[1], E[1], N1, rp01};
        RP c = {ed[2], E[2], N0, rp10};
        RP d = {ed[3], E[3], N1, rp11};
        dim3 grid((maxE + 255) / 256, 4);
        rowptr4_kernel<<<grid, 256, 0, stream>>>(a, b, c, d);
    }
    pack_w2_kernel<<<4, 128, 0, stream>>>(gw2[0], gw2[1], gw2[2], gw2[3], w2pack);

    // loop-invariant precomputation
    lift_kernel<<<N0, 128, 0, stream>>>(samples, lift_w, lift_b, v_down0, N0);
    matmul128_kernel<<<(N0 + 7) / 8, 128, 0, stream>>>(v_down0, W0_w, W0_b, w0term, N0);

    const int CH0 = 4, CH1 = 2;   // chunk sizes -> ~2048 blocks per gno launch
    // gno00: x=lvl0 (sx=1), y=lvl0 (sy=1), f=v_down0
    gno_kernel<<<(N0 + CH0 - 1) / CH0, 128, 0, stream>>>(coords, N0, 1, 1, v_down0,
        es[0], rp00, N0, CH0, gw1[0], gb1[0], w2pack + 0 * 8192, gb2[0],
        nullptr, nullptr, 0, gno00o, nullptr, nullptr, nullptr);
    // gno01 base: x=lvl1 (sx=2), y=lvl0 (sy=1), f=v_down0
    gno_kernel<<<(N1 + CH1 - 1) / CH1, 128, 0, stream>>>(coords, N0, 2, 1, v_down0,
        es[1], rp01, N1, CH1, gw1[1], gb1[1], w2pack + 1 * 8192, gb2[1],
        nullptr, nullptr, 0, gno01b, nullptr, nullptr, nullptr);

    // 3 iterations of the coarse-level recursion
    for (int it = 0; it < 3; ++it) {
        fused_relu_mm_kernel<<<(N1 + 7) / 8, 128, 0, stream>>>(
            gno01b, (it == 0) ? nullptr : v_up1, v_down1, W1_w, W1_b, w1term, N1);
        gno_kernel<<<(N1 + CH1 - 1) / CH1, 128, 0, stream>>>(coords, N0, 2, 2, v_down1,
            es[3], rp11, N1, CH1, gw1[3], gb1[3], w2pack + 3 * 8192, gb2[3],
            w1term, nullptr, 1, v_up1, nullptr, nullptr, nullptr);
    }

    // final upward pass + fused projection
    gno_kernel<<<(N0 + CH0 - 1) / CH0, 128, 0, stream>>>(coords, N0, 1, 2, v_up1,
        es[2], rp10, N0, CH0, gw1[2], gb1[2], w2pack + 2 * 8192, gb2[2],
        w0term, gno00o, 1, nullptr, proj_w, proj_b, (float*)d_out);
}

// Round 7
// 442.752 us; speedup vs baseline: 1.0265x; 1.0265x over previous
//
#include <hip/hip_runtime.h>
#include <hip/hip_bf16.h>

typedef __attribute__((ext_vector_type(8))) short s8;   // 8 bf16 = 4 VGPRs
typedef __attribute__((ext_vector_type(4))) float f4;

#define TILE 64

// gelu tanh-approx (JAX approximate=True), algebraically reduced:
// gelu(x) = x * (1 - 1/(exp(k)+1)),  k = x*(1.59576912 + 0.07135482 x^2)
__device__ __forceinline__ float gelu_fast(float x) {
    float x2 = x * x;
    float k  = x * fmaf(x2, 0.07135481624f, 1.59576912161f);
    float e  = __expf(k);
    float r  = __builtin_amdgcn_rcpf(e + 1.f);
    return x - x * r;
}

__device__ __forceinline__ short f2bf_bits(float v) {
    __hip_bfloat16 b = __float2bfloat16(v);
    return *(short*)&b;
}

struct RP { const int* edst; int E; int N; int* rowptr; };

// Build CSR row pointers for all 4 graphs (edst sorted ascending).
__global__ void rowptr4_kernel(RP a, RP b, RP c, RP d) {
    RP g = (blockIdx.y == 0) ? a : (blockIdx.y == 1) ? b : (blockIdx.y == 2) ? c : d;
    int i = blockIdx.x * blockDim.x + threadIdx.x;
    if (i >= g.E) return;
    int dd = g.edst[i];
    int p  = (i == 0) ? -1 : g.edst[i - 1];
    for (int r = p + 1; r <= dd; ++r) g.rowptr[r] = i;
    if (i == g.E - 1)
        for (int r = dd + 1; r <= g.N; ++r) g.rowptr[r] = g.E;
}

// Pack w2 (64x128 f32, row-major [k][ch]) into MFMA B-fragment order, bf16.
// group g = ((w*4+T)*2+s); lane holds 8 bf16: k = s*32+q*8+j, ch = 64w+4n+T
// (channel remap keeps f_y gathers / acc stores as float4 in true channel order).
__global__ __launch_bounds__(128) void pack_w2_kernel(
    const float* __restrict__ wa, const float* __restrict__ wb,
    const float* __restrict__ wc, const float* __restrict__ wd,
    short* __restrict__ out)
{
    const float* w2 = (blockIdx.x == 0) ? wa : (blockIdx.x == 1) ? wb
                    : (blockIdx.x == 2) ? wc : wd;
    short* dst = out + (size_t)blockIdx.x * 8192;
    const int t = threadIdx.x;
    const int w = t >> 6, lane = t & 63, q = (lane >> 4), n = lane & 15;
#pragma unroll
    for (int T = 0; T < 4; ++T)
#pragma unroll
        for (int s = 0; s < 2; ++s)
#pragma unroll
            for (int j = 0; j < 8; ++j) {
                int k  = s * 32 + q * 8 + j;
                int ch = 64 * w + 4 * n + T;
                dst[((((w * 4 + T) * 2 + s) * 64) + lane) * 8 + j] =
                    f2bf_bits(w2[k * 128 + ch]);
            }
}

// Edge-tile GNO: block = 64 contiguous edges (dst-sorted). Segments found by
// ballot; per-segment accumulate via MFMA groups of 16; atomicAdd raw sums
// into acc[d][c]. Mean/add/relu happen in a separate epilogue kernel.
__global__ __launch_bounds__(128) void gno_edge_kernel(
    const float* __restrict__ coords, int n0, int sx, int sy,
    const float* __restrict__ f_y,
    const int* __restrict__ esrc, const int* __restrict__ edst, int E,
    const float* __restrict__ w1, const float* __restrict__ b1,
    const short* __restrict__ w2bf, const float* __restrict__ b2,
    float* __restrict__ acc)
{
    const int t = threadIdx.x;
    const int w = t >> 6, lane = t & 63, q = lane >> 4, n = lane & 15;
    const int e0 = blockIdx.x * TILE;
    const int te = min(TILE, E - e0);

    __shared__ int   s_src[TILE], s_dst[TILE];
    __shared__ float s_yx[TILE], s_yy[TILE], s_xx[TILE], s_xy[TILE];
    __shared__ __align__(16) short s_gb[2][16 * 72];

    // coalesced staging: wave0 handles src side, wave1 handles dst side
    if (t < TILE) {
        int e = min(e0 + t, E - 1);
        int sv = esrc[e];
        s_src[t] = sv;
        s_yx[t]  = coords[(long)sv * sy];
        s_yy[t]  = coords[n0 + (long)sv * sy];
    } else {
        int l = t - TILE;
        int e = min(e0 + l, E - 1);
        int dv = edst[e];
        s_dst[l] = dv;
        s_xx[l]  = coords[(long)dv * sx];
        s_xy[l]  = coords[n0 + (long)dv * sx];
    }

    // per-block weight prologue (amortized over exactly 4 MFMA groups)
    const float rw0 = w1[lane], rw1v = w1[64 + lane];
    const float rwx = w1[128 + lane], rwy = w1[192 + lane], rb1 = b1[lane];
    s8 bfrag[4][2];
    const s8* w2f = (const s8*)w2bf;
#pragma unroll
    for (int T = 0; T < 4; ++T)
#pragma unroll
        for (int s = 0; s < 2; ++s)
            bfrag[T][s] = w2f[((w * 4 + T) * 2 + s) * 64 + lane];
    const f4 b2c = *(const f4*)&b2[w * 64 + 4 * n];

    __syncthreads();

    // segment-end mask (both waves compute identical mask over lane ids)
    bool fl = (lane < te) && (lane == te - 1 || s_dst[lane + 1] != s_dst[lane]);
    unsigned long long segmask = __ballot(fl);

    int gbp = 0;
    int a = 0;
    while (a < te) {
        const int b = a + 1 + (int)__builtin_ctzll(segmask >> a);
        const int dcur = s_dst[a];
        f4 accr = {0.f, 0.f, 0.f, 0.f};

        for (int g0 = a; g0 < b; g0 += 16) {
            const int cnt = min(16, b - g0);
            // f_y gather (float4, true channel order) — issued early for overlap
            f4 fv[4];
#pragma unroll
            for (int r = 0; r < 4; ++r) {
                int m = q * 4 + r;
                if (m < cnt) {
                    long srow = (long)s_src[g0 + m] * 128;
                    fv[r] = *(const f4*)&f_y[srow + w * 64 + 4 * n];
                } else {
                    f4 z = {0.f, 0.f, 0.f, 0.f};
                    fv[r] = z;
                }
            }
            // layer1: group-local edge j = 2*i + w, hidden = lane
#pragma unroll
            for (int i = 0; i < 8; ++i) {
                int j = 2 * i + w;
                int p = min(g0 + j, te - 1);   // pad rows killed by fv=0
                float x = fmaf(s_yx[p], rw0, fmaf(s_yy[p], rw1v,
                          fmaf(s_xx[p], rwx, fmaf(s_xy[p], rwy, rb1))));
                s_gb[gbp][j * 72 + lane] = f2bf_bits(gelu_fast(x));
            }
            __syncthreads();
            // layer2 MFMA: A m=edge (lane&15), k=q*8+j
            const s8 a0 = *(const s8*)&s_gb[gbp][n * 72 + q * 8];
            const s8 a1 = *(const s8*)&s_gb[gbp][n * 72 + q * 8 + 32];
            f4 c[4];
#pragma unroll
            for (int T = 0; T < 4; ++T) {
                f4 z = {0.f, 0.f, 0.f, 0.f};
                z = __builtin_amdgcn_mfma_f32_16x16x32_bf16(a0, bfrag[T][0], z, 0, 0, 0);
                c[T] = __builtin_amdgcn_mfma_f32_16x16x32_bf16(a1, bfrag[T][1], z, 0, 0, 0);
            }
#pragma unroll
            for (int r = 0; r < 4; ++r)
#pragma unroll
                for (int T = 0; T < 4; ++T)
                    accr[T] += (c[T][r] + b2c[T]) * fv[r][T];
            gbp ^= 1;
        }

        // quad-reduce and flush segment sum (device-scope atomics)
#pragma unroll
        for (int T = 0; T < 4; ++T) {
            float v = accr[T];
            v += __shfl_xor(v, 16, 64);
            v += __shfl_xor(v, 32, 64);
            if (q == 0)
                atomicAdd(&acc[(long)dcur * 128 + w * 64 + 4 * n + T], v);
        }
        a = b;
    }
}

// grid-stride float4 zero fill (n multiple of 4)
__global__ void zero_kernel(float* __restrict__ p, long n) {
    long i = ((long)blockIdx.x * 256 + threadIdx.x) * 4;
    if (i < n) { f4 z = {0.f, 0.f, 0.f, 0.f}; *(f4*)&p[i] = z; }
}

// in-place epilogue: acc[d,c] = [relu]( acc[d,c]/max(deg,1) [+ add0] )
__global__ __launch_bounds__(256) void epi_kernel(
    float* __restrict__ acc, const int* __restrict__ rowptr,
    const float* __restrict__ add0, int do_relu, int N)
{
    long idx = (long)blockIdx.x * 256 + threadIdx.x;
    if (idx >= (long)N * 128) return;
    int d = idx >> 7;
    float deg = (float)(rowptr[d + 1] - rowptr[d]);
    float res = acc[idx] / fmaxf(deg, 1.f);
    if (add0) res += add0[idx];
    if (do_relu) res = fmaxf(res, 0.f);
    acc[idx] = res;
}

// final epilogue + projection: out[d,0:3] = relu(acc/deg + add0 + add1) @ projw + projb
__global__ __launch_bounds__(128) void epi_proj_kernel(
    const float* __restrict__ acc, const int* __restrict__ rowptr,
    const float* __restrict__ add0, const float* __restrict__ add1,
    const float* __restrict__ projw, const float* __restrict__ projb,
    float* __restrict__ fout, int N)
{
    const int d = blockIdx.x, t = threadIdx.x;
    float deg = (float)(rowptr[d + 1] - rowptr[d]);
    long o = (long)d * 128 + t;
    float res = fmaxf(acc[o] / fmaxf(deg, 1.f) + add0[o] + add1[o], 0.f);
    float p0 = res * projw[t * 3 + 0];
    float p1 = res * projw[t * 3 + 1];
    float p2 = res * projw[t * 3 + 2];
#pragma unroll
    for (int off = 32; off > 0; off >>= 1) {
        p0 += __shfl_down(p0, off);
        p1 += __shfl_down(p1, off);
        p2 += __shfl_down(p2, off);
    }
    __shared__ float sred[6];
    if ((t & 63) == 0) { int w = t >> 6; sred[w * 3 + 0] = p0; sred[w * 3 + 1] = p1; sred[w * 3 + 2] = p2; }
    __syncthreads();
    if (t < 3) fout[d * 3 + t] = sred[t] + sred[3 + t] + projb[t];
}

// v_down1 = relu(base + addl); w1out = v_down1 @ W + bias
__global__ __launch_bounds__(128) void fused_relu_mm_kernel(
    const float* __restrict__ base, const float* __restrict__ addl,
    float* __restrict__ vout,
    const float* __restrict__ W, const float* __restrict__ bias,
    float* __restrict__ out, int R)
{
    const int r0 = blockIdx.x * 8;
    const int t = threadIdx.x;
    __shared__ float s_x[8 * 128];
#pragma unroll
    for (int j = 0; j < 8; ++j) {
        int r = r0 + j;
        if (r < R) {
            long o = (long)r * 128 + t;
            float v = base[o] + (addl ? addl[o] : 0.f);
            v = fmaxf(v, 0.f);
            s_x[j * 128 + t] = v;
            vout[o] = v;
        } else s_x[j * 128 + t] = 0.f;
    }
    __syncthreads();
    float acc[8];
    const float bc = bias[t];
#pragma unroll
    for (int j = 0; j < 8; ++j) acc[j] = bc;
    for (int hh = 0; hh < 128; ++hh) {
        float wv = W[hh * 128 + t];
#pragma unroll
        for (int j = 0; j < 8; ++j) acc[j] += s_x[j * 128 + hh] * wv;
    }
#pragma unroll
    for (int j = 0; j < 8; ++j) {
        int r = r0 + j;
        if (r < R) out[(long)r * 128 + t] = acc[j];
    }
}

// plain matmul (for W0 term): out = X @ W + bias
__global__ __launch_bounds__(128) void matmul128_kernel(
    const float* __restrict__ X, const float* __restrict__ W,
    const float* __restrict__ bias, float* __restrict__ out, int R)
{
    const int r0 = blockIdx.x * 8;
    const int t = threadIdx.x;
    __shared__ float s_x[8 * 128];
#pragma unroll
    for (int j = 0; j < 8; ++j) {
        int r = r0 + j;
        s_x[j * 128 + t] = (r < R) ? X[(long)r * 128 + t] : 0.f;
    }
    __syncthreads();
    float acc[8];
    const float bc = bias[t];
#pragma unroll
    for (int j = 0; j < 8; ++j) acc[j] = bc;
    for (int hh = 0; hh < 128; ++hh) {
        float wv = W[hh * 128 + t];
#pragma unroll
        for (int j = 0; j < 8; ++j) acc[j] += s_x[j * 128 + hh] * wv;
    }
#pragma unroll
    for (int j = 0; j < 8; ++j) {
        int r = r0 + j;
        if (r < R) out[(long)r * 128 + t] = acc[j];
    }
}

// v_down0 = samples @ lift_w + lift_b
__global__ __launch_bounds__(128) void lift_kernel(
    const float* __restrict__ samples, const float* __restrict__ W,
    const float* __restrict__ bias, float* __restrict__ out, int N)
{
    const int i = blockIdx.x;
    const int t = threadIdx.x;
    float s0 = samples[i * 3 + 0];
    float s1 = samples[i * 3 + 1];
    float s2 = samples[i * 3 + 2];
    out[(long)i * 128 + t] = s0 * W[t] + s1 * W[128 + t] + s2 * W[256 + t] + bias[t];
}

extern "C" void kernel_launch(void* const* d_in, const int* in_sizes, int n_in,
                              void* d_out, int out_size, void* d_ws, size_t ws_size,
                              hipStream_t stream)
{
    const float* coords  = (const float*)d_in[0];
    const float* samples = (const float*)d_in[1];
    // d_in[2] = sigma (unused)
    const float* lift_w  = (const float*)d_in[3];
    const float* lift_b  = (const float*)d_in[4];
    const float* proj_w  = (const float*)d_in[5];
    const float* proj_b  = (const float*)d_in[6];
    const float* W0_w    = (const float*)d_in[7];
    const float* W0_b    = (const float*)d_in[8];
    const float* W1_w    = (const float*)d_in[9];
    const float* W1_b    = (const float*)d_in[10];
    const float *gw1[4], *gb1[4], *gw2[4], *gb2[4];   // 0=gk00,1=gk01,2=gk10,3=gk11
    for (int g = 0; g < 4; ++g) {
        gw1[g] = (const float*)d_in[11 + 4 * g + 0];
        gb1[g] = (const float*)d_in[11 + 4 * g + 1];
        gw2[g] = (const float*)d_in[11 + 4 * g + 2];
        gb2[g] = (const float*)d_in[11 + 4 * g + 3];
    }
    const int* es[4]; const int* ed[4]; int E[4];
    for (int g = 0; g < 4; ++g) {
        es[g] = (const int*)d_in[27 + 2 * g];
        ed[g] = (const int*)d_in[27 + 2 * g + 1];
        E[g]  = in_sizes[27 + 2 * g];
    }

    const int N0 = in_sizes[0] / 2;     // 8192
    const int N1 = (N0 + 1) / 2;        // 4096

    float* ws = (float*)d_ws;
    float* v_down0 = ws;                              // N0*128 (reused as acc10)
    float* w0term  = v_down0 + (size_t)N0 * 128;      // N0*128
    float* gno00o  = w0term  + (size_t)N0 * 128;      // N0*128 (acc00, epi in place)
    float* gno01b  = gno00o  + (size_t)N0 * 128;      // N1*128 (acc01, epi in place)
    float* v_down1 = gno01b  + (size_t)N1 * 128;      // N1*128
    float* w1term  = v_down1 + (size_t)N1 * 128;      // N1*128
    float* v_up1   = w1term  + (size_t)N1 * 128;      // N1*128 (acc11, epi in place)
    short* w2pack  = (short*)(v_up1 + (size_t)N1 * 128);  // 4*8192 bf16
    int*   rp      = (int*)(w2pack + 4 * 8192);
    int* rp00 = rp;                // N0+1
    int* rp01 = rp00 + (N0 + 1);   // N1+1
    int* rp10 = rp01 + (N1 + 1);   // N0+1
    int* rp11 = rp10 + (N0 + 1);   // N1+1

    // CSR row pointers (degrees for epilogue means)
    {
        int maxE = E[0];
        for (int g = 1; g < 4; ++g) maxE = max(maxE, E[g]);
        RP a = {ed[0], E[0], N0, rp00};
        RP b = {ed[1], E[1], N1, rp01};
        RP c = {ed[2], E[2], N0, rp10};
        RP d = {ed[3], E[3], N1, rp11};
        dim3 grid((maxE + 255) / 256, 4);
        rowptr4_kernel<<<grid, 256, 0, stream>>>(a, b, c, d);
    }
    pack_w2_kernel<<<4, 128, 0, stream>>>(gw2[0], gw2[1], gw2[2], gw2[3], w2pack);

    lift_kernel<<<N0, 128, 0, stream>>>(samples, lift_w, lift_b, v_down0, N0);
    matmul128_kernel<<<(N0 + 7) / 8, 128, 0, stream>>>(v_down0, W0_w, W0_b, w0term, N0);

    const long n00 = (long)N0 * 128, n11 = (long)N1 * 128;

    // gno00 + gno01 (loop-invariant): zero both acc buffers (contiguous), run, epi
    zero_kernel<<<(int)((n00 + n11) / 4 + 255) / 256, 256, 0, stream>>>(gno00o, n00 + n11);
    gno_edge_kernel<<<(E[0] + TILE - 1) / TILE, 128, 0, stream>>>(coords, N0, 1, 1,
        v_down0, es[0], ed[0], E[0], gw1[0], gb1[0], w2pack + 0 * 8192, gb2[0], gno00o);
    gno_edge_kernel<<<(E[1] + TILE - 1) / TILE, 128, 0, stream>>>(coords, N0, 2, 1,
        v_down0, es[1], ed[1], E[1], gw1[1], gb1[1], w2pack + 1 * 8192, gb2[1], gno01b);
    epi_kernel<<<(int)(n00 + 255) / 256, 256, 0, stream>>>(gno00o, rp00, nullptr, 0, N0);
    epi_kernel<<<(int)(n11 + 255) / 256, 256, 0, stream>>>(gno01b, rp01, nullptr, 0, N1);

    // 3 iterations of the coarse-level recursion
    for (int it = 0; it < 3; ++it) {
        fused_relu_mm_kernel<<<(N1 + 7) / 8, 128, 0, stream>>>(
            gno01b, (it == 0) ? nullptr : v_up1, v_down1, W1_w, W1_b, w1term, N1);
        zero_kernel<<<(int)(n11 / 4 + 255) / 256, 256, 0, stream>>>(v_up1, n11);
        gno_edge_kernel<<<(E[3] + TILE - 1) / TILE, 128, 0, stream>>>(coords, N0, 2, 2,
            v_down1, es[3], ed[3], E[3], gw1[3], gb1[3], w2pack + 3 * 8192, gb2[3], v_up1);
        epi_kernel<<<(int)(n11 + 255) / 256, 256, 0, stream>>>(v_up1, rp11, w1term, 1, N1);
    }

    // final upward pass (acc10 reuses v_down0, which is dead now) + fused projection
    zero_kernel<<<(int)(n00 / 4 + 255) / 256, 256, 0, stream>>>(v_down0, n00);
    gno_edge_kernel<<<(E[2] + TILE - 1) / TILE, 128, 0, stream>>>(coords, N0, 1, 2,
        v_up1, es[2], ed[2], E[2], gw1[2], gb1[2], w2pack + 2 * 8192, gb2[2], v_down0);
    epi_proj_kernel<<<N0, 128, 0, stream>>>(v_down0, rp10, w0term, gno00o,
        proj_w, proj_b, (float*)d_out, N0);
}

// Round 8
// 379.600 us; speedup vs baseline: 1.1973x; 1.1664x over previous
//
#include <hip/hip_runtime.h>
#include <hip/hip_bf16.h>

typedef __attribute__((ext_vector_type(8))) short s8;   // 8 bf16 = 4 VGPRs
typedef __attribute__((ext_vector_type(4))) float f4;

#define TILE 128

// gelu tanh-approx (JAX approximate=True), algebraically reduced:
// gelu(x) = x * (1 - 1/(exp(k)+1)),  k = x*(1.59576912 + 0.07135482 x^2)
__device__ __forceinline__ float gelu_fast(float x) {
    float x2 = x * x;
    float k  = x * fmaf(x2, 0.07135481624f, 1.59576912161f);
    float e  = __expf(k);
    float r  = __builtin_amdgcn_rcpf(e + 1.f);
    return x - x * r;
}

__device__ __forceinline__ short f2bf_bits(float v) {
    __hip_bfloat16 b = __float2bfloat16(v);
    return *(short*)&b;
}

struct RP { const int* edst; int E; int N; int* rowptr; };

__global__ void rowptr4_kernel(RP a, RP b, RP c, RP d) {
    RP g = (blockIdx.y == 0) ? a : (blockIdx.y == 1) ? b : (blockIdx.y == 2) ? c : d;
    int i = blockIdx.x * blockDim.x + threadIdx.x;
    if (i >= g.E) return;
    int dd = g.edst[i];
    int p  = (i == 0) ? -1 : g.edst[i - 1];
    for (int r = p + 1; r <= dd; ++r) g.rowptr[r] = i;
    if (i == g.E - 1)
        for (int r = dd + 1; r <= g.N; ++r) g.rowptr[r] = g.E;
}

// Pack w2 into MFMA B-fragment order (bf16), channel remap ch = 64w+4n+T.
__global__ __launch_bounds__(128) void pack_w2_kernel(
    const float* __restrict__ wa, const float* __restrict__ wb,
    const float* __restrict__ wc, const float* __restrict__ wd,
    short* __restrict__ out)
{
    const float* w2 = (blockIdx.x == 0) ? wa : (blockIdx.x == 1) ? wb
                    : (blockIdx.x == 2) ? wc : wd;
    short* dst = out + (size_t)blockIdx.x * 8192;
    const int t = threadIdx.x;
    const int w = t >> 6, lane = t & 63, q = (lane >> 4), n = lane & 15;
#pragma unroll
    for (int T = 0; T < 4; ++T)
#pragma unroll
        for (int s = 0; s < 2; ++s)
#pragma unroll
            for (int j = 0; j < 8; ++j) {
                int k  = s * 32 + q * 8 + j;
                int ch = 64 * w + 4 * n + T;
                dst[((((w * 4 + T) * 2 + s) * 64) + lane) * 8 + j] =
                    f2bf_bits(w2[k * 128 + ch]);
            }
}

struct GnoP {
    const float* fy;
    const int* esrc;
    const int* edst;
    const float* w1;
    const float* b1;
    const short* w2;
    const float* b2;
    float* acc;
    int E, sx, sy, pad;
};

__device__ __forceinline__ int seg_end(unsigned long long m0, unsigned long long m1, int a) {
    if (a < 64) {
        unsigned long long r = m0 >> a;
        if (r) return a + (int)__builtin_ctzll(r) + 1;
        return 64 + (int)__builtin_ctzll(m1) + 1;
    }
    unsigned long long r = m1 >> (a - 64);
    return a + (int)__builtin_ctzll(r) + 1;
}

// Edge-tile GNO, merged two-graph launch. Block = 128 edges, 8 MFMA groups.
// Layer1 f32 VALU -> bf16 LDS; layer2 MFMA; f_y gather software-pipelined;
// per-segment quad-reduce -> atomicAdd raw sums into acc.
__global__ __launch_bounds__(128) void gno_edge_kernel(
    const float* __restrict__ coords, int n0, GnoP A, GnoP B, int ntA)
{
    const GnoP P = (blockIdx.x < ntA) ? A : B;
    const int tile = (blockIdx.x < ntA) ? blockIdx.x : blockIdx.x - ntA;
    const int t = threadIdx.x;
    const int w = t >> 6, lane = t & 63, q = lane >> 4, n = lane & 15;
    const int e0 = tile * TILE;
    const int te = min(TILE, P.E - e0);

    __shared__ __align__(16) float s_crd[TILE][4];
    __shared__ int s_off[TILE];
    __shared__ int s_dst[TILE];
    __shared__ unsigned long long s_mask[2];
    __shared__ __align__(16) short s_gb[2][16 * 72];

    // stage edge t: src+dst coords interleaved as float4, prescaled f_y offset
    {
        int e = min(e0 + t, P.E - 1);
        int sv = P.esrc[e];
        int dv = P.edst[e];
        s_off[t] = sv * 128;
        s_dst[t] = dv;
        s_crd[t][0] = coords[(long)sv * P.sy];
        s_crd[t][1] = coords[n0 + (long)sv * P.sy];
        s_crd[t][2] = coords[(long)dv * P.sx];
        s_crd[t][3] = coords[n0 + (long)dv * P.sx];
    }

    // per-block weight prologue
    const float rw0 = P.w1[lane], rw1v = P.w1[64 + lane];
    const float rwx = P.w1[128 + lane], rwy = P.w1[192 + lane], rb1 = P.b1[lane];
    s8 bfrag[4][2];
    const s8* w2f = (const s8*)P.w2;
#pragma unroll
    for (int T = 0; T < 4; ++T)
#pragma unroll
        for (int s = 0; s < 2; ++s)
            bfrag[T][s] = w2f[((w * 4 + T) * 2 + s) * 64 + lane];
    const f4 b2c = *(const f4*)&P.b2[w * 64 + 4 * n];

    __syncthreads();

    // segment-end masks, one 64-bit mask per wave's edge range
    {
        int idx = w * 64 + lane;
        bool fl = (idx < te) && (idx == te - 1 || s_dst[idx + 1] != s_dst[idx]);
        unsigned long long m = __ballot(fl);
        if (lane == 0) s_mask[w] = m;
    }
    __syncthreads();
    const unsigned long long m0 = s_mask[0], m1 = s_mask[1];

    // software-pipelined group loop
    int g0 = 0;
    int b = seg_end(m0, m1, 0);
    f4 fvc[4];
#pragma unroll
    for (int r = 0; r < 4; ++r) {
        int row = q * 4 + r;
        if (row < b) fvc[r] = *(const f4*)&P.fy[(long)s_off[row] + w * 64 + 4 * n];
        else { f4 z = {0.f, 0.f, 0.f, 0.f}; fvc[r] = z; }
    }
    f4 accr = {0.f, 0.f, 0.f, 0.f};
    int gbp = 0;

    while (true) {
        int gn = g0 + 16, bn = b;
        const bool endseg = (gn >= b);
        if (endseg) { gn = b; if (gn < te) bn = seg_end(m0, m1, gn); }
        // prefetch next group's f_y (consumed next iteration)
        f4 fvn[4];
        if (gn < te) {
#pragma unroll
            for (int r = 0; r < 4; ++r) {
                int row = gn + q * 4 + r;
                if (row < bn) fvn[r] = *(const f4*)&P.fy[(long)s_off[row] + w * 64 + 4 * n];
                else { f4 z = {0.f, 0.f, 0.f, 0.f}; fvn[r] = z; }
            }
        }
        // layer1: group rows g0+j, j = 2*i+w; hidden = lane
#pragma unroll
        for (int i = 0; i < 8; ++i) {
            int j = 2 * i + w;
            int p = min(g0 + j, te - 1);
            const f4 crd = *(const f4*)s_crd[p];
            float x = fmaf(crd.x, rw0, fmaf(crd.y, rw1v,
                      fmaf(crd.z, rwx, fmaf(crd.w, rwy, rb1))));
            s_gb[gbp][j * 72 + lane] = f2bf_bits(gelu_fast(x));
        }
        __syncthreads();
        // layer2 MFMA
        const s8 a0 = *(const s8*)&s_gb[gbp][n * 72 + q * 8];
        const s8 a1 = *(const s8*)&s_gb[gbp][n * 72 + q * 8 + 32];
        f4 c[4];
#pragma unroll
        for (int T = 0; T < 4; ++T) {
            f4 z = {0.f, 0.f, 0.f, 0.f};
            z = __builtin_amdgcn_mfma_f32_16x16x32_bf16(a0, bfrag[T][0], z, 0, 0, 0);
            c[T] = __builtin_amdgcn_mfma_f32_16x16x32_bf16(a1, bfrag[T][1], z, 0, 0, 0);
        }
#pragma unroll
        for (int r = 0; r < 4; ++r)
#pragma unroll
            for (int T = 0; T < 4; ++T)
                accr[T] += (c[T][r] + b2c[T]) * fvc[r][T];
        if (endseg) {
            const int dcur = s_dst[g0];
#pragma unroll
            for (int T = 0; T < 4; ++T) {
                float v = accr[T];
                v += __shfl_xor(v, 16, 64);
                v += __shfl_xor(v, 32, 64);
                if (q == 0)
                    atomicAdd(&P.acc[(long)dcur * 128 + w * 64 + 4 * n + T], v);
            }
            f4 z = {0.f, 0.f, 0.f, 0.f};
            accr = z;
        }
        if (gn >= te) break;
        g0 = gn; b = bn;
#pragma unroll
        for (int r = 0; r < 4; ++r) fvc[r] = fvn[r];
        gbp ^= 1;
    }
}

// grid-stride float4 zero fill (n multiple of 4)
__global__ void zero_kernel(float* __restrict__ p, long n) {
    long i = ((long)blockIdx.x * 256 + threadIdx.x) * 4;
    if (i < n) { f4 z = {0.f, 0.f, 0.f, 0.f}; *(f4*)&p[i] = z; }
}

// epilogue for gno00+gno01 (contiguous acc buffers) + zero the gno10 acc
__global__ __launch_bounds__(256) void epi0001_kernel(
    float* __restrict__ acc, const int* __restrict__ rp00, int N0,
    const int* __restrict__ rp01, float* __restrict__ vd0zero, long ntot)
{
    long idx = (long)blockIdx.x * 256 + threadIdx.x;
    if (idx >= ntot) return;
    int d = (int)(idx >> 7);
    float deg;
    if (d < N0) { deg = (float)(rp00[d + 1] - rp00[d]); vd0zero[idx] = 0.f; }
    else        { deg = (float)(rp01[d - N0 + 1] - rp01[d - N0]); }
    acc[idx] = acc[idx] / fmaxf(deg, 1.f);
}

// fused: u = relu(accu/deg + w1t)   (accu!=null; zero accu after read)
//        vd1 = relu(base + u); w1t = vd1 @ W + bias   (w1t in/out, row-local)
// it0: accu=null -> vd1 = relu(base); zbuf zeroed.
__global__ __launch_bounds__(128) void relu_mm_kernel(
    const float* __restrict__ base, float* __restrict__ accu,
    const int* __restrict__ rowptr, float* __restrict__ w1t,
    const float* __restrict__ W, const float* __restrict__ bias,
    float* __restrict__ vout, float* __restrict__ zbuf, int R)
{
    const int r0 = blockIdx.x * 8;
    const int t = threadIdx.x;
    __shared__ float s_x[8 * 128];
#pragma unroll
    for (int j = 0; j < 8; ++j) {
        int r = r0 + j;
        long o = (long)r * 128 + t;
        float v = base[o];
        if (accu) {
            float deg = (float)(rowptr[r + 1] - rowptr[r]);
            float u = fmaxf(accu[o] / fmaxf(deg, 1.f) + w1t[o], 0.f);
            v += u;
            accu[o] = 0.f;
        } else if (zbuf) {
            zbuf[o] = 0.f;
        }
        v = fmaxf(v, 0.f);
        s_x[j * 128 + t] = v;
        vout[o] = v;
    }
    __syncthreads();
    float acc[8];
    const float bc = bias[t];
#pragma unroll
    for (int j = 0; j < 8; ++j) acc[j] = bc;
    for (int hh = 0; hh < 128; ++hh) {
        float wv = W[hh * 128 + t];
#pragma unroll
        for (int j = 0; j < 8; ++j) acc[j] += s_x[j * 128 + hh] * wv;
    }
#pragma unroll
    for (int j = 0; j < 8; ++j)
        w1t[(long)(r0 + j) * 128 + t] = acc[j];
}

// final gno11 epilogue (it2): v_up1 = relu(acc/deg + w1t), in place
__global__ __launch_bounds__(256) void epi11_kernel(
    float* __restrict__ acc, const int* __restrict__ rowptr,
    const float* __restrict__ w1t, int N)
{
    long idx = (long)blockIdx.x * 256 + threadIdx.x;
    if (idx >= (long)N * 128) return;
    int d = (int)(idx >> 7);
    float deg = (float)(rowptr[d + 1] - rowptr[d]);
    acc[idx] = fmaxf(acc[idx] / fmaxf(deg, 1.f) + w1t[idx], 0.f);
}

// fused lift + W0 matmul: v_down0 row, then w0term = v_down0 @ W0 + b
__global__ __launch_bounds__(128) void lift_mm_kernel(
    const float* __restrict__ samples, const float* __restrict__ LW,
    const float* __restrict__ Lb, const float* __restrict__ W0,
    const float* __restrict__ W0b, float* __restrict__ vout,
    float* __restrict__ w0t, int R)
{
    const int r0 = blockIdx.x * 8;
    const int t = threadIdx.x;
    __shared__ float s_x[8 * 128];
#pragma unroll
    for (int j = 0; j < 8; ++j) {
        int r = r0 + j;
        float s0 = samples[r * 3 + 0], s1 = samples[r * 3 + 1], s2 = samples[r * 3 + 2];
        float v = s0 * LW[t] + s1 * LW[128 + t] + s2 * LW[256 + t] + Lb[t];
        s_x[j * 128 + t] = v;
        vout[(long)r * 128 + t] = v;
    }
    __syncthreads();
    float acc[8];
    const float bc = W0b[t];
#pragma unroll
    for (int j = 0; j < 8; ++j) acc[j] = bc;
    for (int hh = 0; hh < 128; ++hh) {
        float wv = W0[hh * 128 + t];
#pragma unroll
        for (int j = 0; j < 8; ++j) acc[j] += s_x[j * 128 + hh] * wv;
    }
#pragma unroll
    for (int j = 0; j < 8; ++j)
        w0t[(long)(r0 + j) * 128 + t] = acc[j];
}

// final epilogue + projection
__global__ __launch_bounds__(128) void epi_proj_kernel(
    const float* __restrict__ acc, const int* __restrict__ rowptr,
    const float* __restrict__ add0, const float* __restrict__ add1,
    const float* __restrict__ projw, const float* __restrict__ projb,
    float* __restrict__ fout, int N)
{
    const int d = blockIdx.x, t = threadIdx.x;
    float deg = (float)(rowptr[d + 1] - rowptr[d]);
    long o = (long)d * 128 + t;
    float res = fmaxf(acc[o] / fmaxf(deg, 1.f) + add0[o] + add1[o], 0.f);
    float p0 = res * projw[t * 3 + 0];
    float p1 = res * projw[t * 3 + 1];
    float p2 = res * projw[t * 3 + 2];
#pragma unroll
    for (int off = 32; off > 0; off >>= 1) {
        p0 += __shfl_down(p0, off);
        p1 += __shfl_down(p1, off);
        p2 += __shfl_down(p2, off);
    }
    __shared__ float sred[6];
    if ((t & 63) == 0) { int w = t >> 6; sred[w * 3 + 0] = p0; sred[w * 3 + 1] = p1; sred[w * 3 + 2] = p2; }
    __syncthreads();
    if (t < 3) fout[d * 3 + t] = sred[t] + sred[3 + t] + projb[t];
}

extern "C" void kernel_launch(void* const* d_in, const int* in_sizes, int n_in,
                              void* d_out, int out_size, void* d_ws, size_t ws_size,
                              hipStream_t stream)
{
    const float* coords  = (const float*)d_in[0];
    const float* samples = (const float*)d_in[1];
    const float* lift_w  = (const float*)d_in[3];
    const float* lift_b  = (const float*)d_in[4];
    const float* proj_w  = (const float*)d_in[5];
    const float* proj_b  = (const float*)d_in[6];
    const float* W0_w    = (const float*)d_in[7];
    const float* W0_b    = (const float*)d_in[8];
    const float* W1_w    = (const float*)d_in[9];
    const float* W1_b    = (const float*)d_in[10];
    const float *gw1[4], *gb1[4], *gw2[4], *gb2[4];   // 0=gk00,1=gk01,2=gk10,3=gk11
    for (int g = 0; g < 4; ++g) {
        gw1[g] = (const float*)d_in[11 + 4 * g + 0];
        gb1[g] = (const float*)d_in[11 + 4 * g + 1];
        gw2[g] = (const float*)d_in[11 + 4 * g + 2];
        gb2[g] = (const float*)d_in[11 + 4 * g + 3];
    }
    const int* es[4]; const int* ed[4]; int E[4];
    for (int g = 0; g < 4; ++g) {
        es[g] = (const int*)d_in[27 + 2 * g];
        ed[g] = (const int*)d_in[27 + 2 * g + 1];
        E[g]  = in_sizes[27 + 2 * g];
    }

    const int N0 = in_sizes[0] / 2;     // 8192
    const int N1 = (N0 + 1) / 2;        // 4096

    float* ws = (float*)d_ws;
    float* v_down0 = ws;                              // N0*128 (acc10 later)
    float* w0term  = v_down0 + (size_t)N0 * 128;      // N0*128
    float* gno00o  = w0term  + (size_t)N0 * 128;      // N0*128 (acc00)
    float* gno01b  = gno00o  + (size_t)N0 * 128;      // N1*128 (acc01, contiguous)
    float* v_down1 = gno01b  + (size_t)N1 * 128;      // N1*128
    float* w1term  = v_down1 + (size_t)N1 * 128;      // N1*128
    float* v_up1   = w1term  + (size_t)N1 * 128;      // N1*128 (acc11 in place)
    short* w2pack  = (short*)(v_up1 + (size_t)N1 * 128);  // 4*8192 bf16
    int*   rp      = (int*)(w2pack + 4 * 8192);
    int* rp00 = rp;                // N0+1
    int* rp01 = rp00 + (N0 + 1);   // N1+1
    int* rp10 = rp01 + (N1 + 1);   // N0+1
    int* rp11 = rp10 + (N0 + 1);   // N1+1

    {
        int maxE = E[0];
        for (int g = 1; g < 4; ++g) maxE = max(maxE, E[g]);
        RP a = {ed[0], E[0], N0, rp00};
        RP b = {ed[1], E[1], N1, rp01};
        RP c = {ed[2], E[2], N0, rp10};
        RP d = {ed[3], E[3], N1, rp11};
        dim3 grid((maxE + 255) / 256, 4);
        rowptr4_kernel<<<grid, 256, 0, stream>>>(a, b, c, d);
    }
    pack_w2_kernel<<<4, 128, 0, stream>>>(gw2[0], gw2[1], gw2[2], gw2[3], w2pack);

    const long n00 = (long)N0 * 128, n11 = (long)N1 * 128;

    // zero acc00+acc01 (contiguous)
    zero_kernel<<<(int)((n00 + n11) / 4 + 255) / 256, 256, 0, stream>>>(gno00o, n00 + n11);
    // v_down0 + w0term (fused)
    lift_mm_kernel<<<N0 / 8, 128, 0, stream>>>(samples, lift_w, lift_b, W0_w, W0_b,
                                               v_down0, w0term, N0);

    GnoP P00 = {v_down0, es[0], ed[0], gw1[0], gb1[0], w2pack + 0 * 8192, gb2[0], gno00o, E[0], 1, 1, 0};
    GnoP P01 = {v_down0, es[1], ed[1], gw1[1], gb1[1], w2pack + 1 * 8192, gb2[1], gno01b, E[1], 2, 1, 0};
    GnoP P11 = {v_down1, es[3], ed[3], gw1[3], gb1[3], w2pack + 3 * 8192, gb2[3], v_up1,  E[3], 2, 2, 0};
    GnoP P10 = {v_up1,   es[2], ed[2], gw1[2], gb1[2], w2pack + 2 * 8192, gb2[2], v_down0, E[2], 1, 2, 0};

    // gno00 + gno01 merged (both read v_down0)
    {
        int tA = (E[0] + TILE - 1) / TILE, tB = (E[1] + TILE - 1) / TILE;
        gno_edge_kernel<<<tA + tB, 128, 0, stream>>>(coords, N0, P00, P01, tA);
    }
    // epilogue for both + zero acc10 (v_down0 is dead as f_y after the next launches? no:
    // v_down0 is f_y ONLY for gno00/gno01, which have completed -> safe to zero here)
    epi0001_kernel<<<(int)((n00 + n11) + 255) / 256, 256, 0, stream>>>(
        gno00o, rp00, N0, rp01, v_down0, n00 + n11);

    for (int it = 0; it < 3; ++it) {
        relu_mm_kernel<<<N1 / 8, 128, 0, stream>>>(
            gno01b, (it == 0) ? nullptr : v_up1, rp11, w1term, W1_w, W1_b,
            v_down1, (it == 0) ? v_up1 : nullptr, N1);
        int tt = (E[3] + TILE - 1) / TILE;
        gno_edge_kernel<<<tt, 128, 0, stream>>>(coords, N0, P11, P11, tt);
    }
    epi11_kernel<<<(int)(n11 + 255) / 256, 256, 0, stream>>>(v_up1, rp11, w1term, N1);

    {
        int tt = (E[2] + TILE - 1) / TILE;
        gno_edge_kernel<<<tt, 128, 0, stream>>>(coords, N0, P10, P10, tt);
    }
    epi_proj_kernel<<<N0, 128, 0, stream>>>(v_down0, rp10, w0term, gno00o,
                                            proj_w, proj_b, (float*)d_out, N0);
}

// Round 9
// 356.516 us; speedup vs baseline: 1.2748x; 1.0648x over previous
//
#include <hip/hip_runtime.h>
#include <hip/hip_bf16.h>

typedef __attribute__((ext_vector_type(8))) short s8;   // 8 bf16 = 4 VGPRs
typedef __attribute__((ext_vector_type(4))) float f4;

#define TILE 128

// gelu tanh-approx (JAX approximate=True), exp2-folded:
// gelu(x) = x - x/(exp2(k2)+1),  k2 = x*(c0 + c1*x^2), c = log2(e)*(1.59576912, 0.07135482)
__device__ __forceinline__ float gelu_fast(float x) {
    float x2 = x * x;
    float k2 = x * fmaf(x2, 0.10294326f, 2.30220819f);
    float e  = __builtin_amdgcn_exp2f(k2);
    float r  = __builtin_amdgcn_rcpf(e + 1.f);
    return fmaf(-x, r, x);
}

__device__ __forceinline__ unsigned pack_bf16x2(float a, float b) {
    __hip_bfloat162 h = __float22bfloat162_rn(make_float2(a, b));
    return *(unsigned*)&h;
}

__device__ __forceinline__ short f2bf_bits(float v) {
    __hip_bfloat16 b = __float2bfloat16(v);
    return *(short*)&b;
}

struct RP { const int* edst; int E; int N; int* rowptr; };

__global__ void rowptr4_kernel(RP a, RP b, RP c, RP d) {
    RP g = (blockIdx.y == 0) ? a : (blockIdx.y == 1) ? b : (blockIdx.y == 2) ? c : d;
    int i = blockIdx.x * blockDim.x + threadIdx.x;
    if (i >= g.E) return;
    int dd = g.edst[i];
    int p  = (i == 0) ? -1 : g.edst[i - 1];
    for (int r = p + 1; r <= dd; ++r) g.rowptr[r] = i;
    if (i == g.E - 1)
        for (int r = dd + 1; r <= g.N; ++r) g.rowptr[r] = g.E;
}

// Pack w2 into MFMA B-fragment order (bf16), channel remap ch = 64w+4n+T.
// 16 blocks: graph = bid>>2, T = bid&3.
__global__ __launch_bounds__(128) void pack_w2_kernel(
    const float* __restrict__ wa, const float* __restrict__ wb,
    const float* __restrict__ wc, const float* __restrict__ wd,
    short* __restrict__ out)
{
    const int g = blockIdx.x >> 2, T = blockIdx.x & 3;
    const float* w2 = (g == 0) ? wa : (g == 1) ? wb : (g == 2) ? wc : wd;
    short* dst = out + (size_t)g * 8192;
    const int t = threadIdx.x;
    const int w = t >> 6, lane = t & 63, q = (lane >> 4), n = lane & 15;
#pragma unroll
    for (int s = 0; s < 2; ++s)
#pragma unroll
        for (int j = 0; j < 8; ++j) {
            int k  = s * 32 + q * 8 + j;
            int ch = 64 * w + 4 * n + T;
            dst[((((w * 4 + T) * 2 + s) * 64) + lane) * 8 + j] =
                f2bf_bits(w2[k * 128 + ch]);
        }
}

struct GnoP {
    const float* fy;
    const int* esrc;
    const int* edst;
    const float* w1;
    const float* b1;
    const short* w2;
    const float* b2;
    float* acc;
    int E, sx, sy, pad;
};

__device__ __forceinline__ int seg_end(unsigned long long m0, unsigned long long m1, int a) {
    if (a < 64) {
        unsigned long long r = m0 >> a;
        if (r) return a + (int)__builtin_ctzll(r) + 1;
        return 64 + (int)__builtin_ctzll(m1) + 1;
    }
    unsigned long long r = m1 >> (a - 64);
    return a + (int)__builtin_ctzll(r) + 1;
}

// Edge-tile GNO, 2-wave blocks, 128 edges/tile, 8 MFMA groups.
// Layer1 (h-pairs) f32 VALU -> packed bf16 LDS; layer2 MFMA with b2 C-init;
// f_y gather pipelined in place; per-segment quad-reduce -> atomicAdd.
__global__ __launch_bounds__(128) void gno_edge_kernel(
    const float* __restrict__ coords, int n0, GnoP A, GnoP B, int ntA)
{
    const GnoP P = (blockIdx.x < ntA) ? A : B;
    const int tile = (blockIdx.x < ntA) ? blockIdx.x : blockIdx.x - ntA;
    const int t = threadIdx.x;
    const int w = t >> 6, lane = t & 63, q = lane >> 4, n = lane & 15;
    const int e0 = tile * TILE;
    const int te = min(TILE, P.E - e0);

    __shared__ __align__(16) float s_crd[(TILE + 16) * 4];
    __shared__ int s_off[TILE];
    __shared__ int s_dst[TILE];
    __shared__ unsigned long long s_mask[2];
    __shared__ __align__(16) short s_gb[2][16 * 72];

    // stage edge t (+ pad rows with any finite coords)
    {
        int e = min(e0 + t, P.E - 1);
        int sv = P.esrc[e];
        int dv = P.edst[e];
        s_off[t] = sv * 128;
        s_dst[t] = dv;
        f4 c4 = {coords[(long)sv * P.sy], coords[n0 + (long)sv * P.sy],
                 coords[(long)dv * P.sx], coords[n0 + (long)dv * P.sx]};
        *(f4*)&s_crd[t * 4] = c4;
        if (t < 16) *(f4*)&s_crd[(TILE + t) * 4] = c4;
    }

    // layer-1 weights for hidden pair h0 = 2*(lane&31), h0+1
    const int h0 = 2 * (lane & 31);
    const float wA0 = P.w1[h0],       wA1 = P.w1[h0 + 1];
    const float wB0 = P.w1[64 + h0],  wB1 = P.w1[65 + h0];
    const float wC0 = P.w1[128 + h0], wC1 = P.w1[129 + h0];
    const float wD0 = P.w1[192 + h0], wD1 = P.w1[193 + h0];
    const float b10 = P.b1[h0],       b11 = P.b1[h0 + 1];

    s8 bfrag[4][2];
    const s8* w2f = (const s8*)P.w2;
#pragma unroll
    for (int T = 0; T < 4; ++T)
#pragma unroll
        for (int s = 0; s < 2; ++s)
            bfrag[T][s] = w2f[((w * 4 + T) * 2 + s) * 64 + lane];
    const f4 b2c = *(const f4*)&P.b2[w * 64 + 4 * n];
    f4 b2i[4];
#pragma unroll
    for (int T = 0; T < 4; ++T) { f4 z = {b2c[T], b2c[T], b2c[T], b2c[T]}; b2i[T] = z; }

    const float* fyl = P.fy + (w * 64 + 4 * n);   // lane's channel base

    __syncthreads();

    {
        int idx = w * 64 + lane;
        bool fl = (idx < te) && (idx == te - 1 || s_dst[idx + 1] != s_dst[idx]);
        unsigned long long m = __ballot(fl);
        if (lane == 0) s_mask[w] = m;
    }
    __syncthreads();
    const unsigned long long m0 = s_mask[0], m1 = s_mask[1];

    int g0 = 0;
    int b = seg_end(m0, m1, 0);
    f4 fvc[4];
#pragma unroll
    for (int r = 0; r < 4; ++r) {
        int row = q * 4 + r;
        if (row < b) fvc[r] = *(const f4*)&fyl[s_off[row]];
        else { f4 z = {0.f, 0.f, 0.f, 0.f}; fvc[r] = z; }
    }
    f4 accr = {0.f, 0.f, 0.f, 0.f};
    int gbp = 0;
    const int jh = lane >> 5;

    while (true) {
        // layer1: 4 pair-iters, j = 4i + 2jh + w covers group rows 0..15
#pragma unroll
        for (int i = 0; i < 4; ++i) {
            int j = 4 * i + 2 * jh + w;
            const f4 crd = *(const f4*)&s_crd[(g0 + j) * 4];
            float x0 = fmaf(crd[0], wA0, fmaf(crd[1], wB0,
                       fmaf(crd[2], wC0, fmaf(crd[3], wD0, b10))));
            float x1 = fmaf(crd[0], wA1, fmaf(crd[1], wB1,
                       fmaf(crd[2], wC1, fmaf(crd[3], wD1, b11))));
            *(unsigned*)&s_gb[gbp][j * 72 + h0] = pack_bf16x2(gelu_fast(x0), gelu_fast(x1));
        }
        __syncthreads();
        // layer2 MFMA: A m=edge (lane&15), k=q*8+j; C init = b2 splat
        const s8 a0 = *(const s8*)&s_gb[gbp][n * 72 + q * 8];
        const s8 a1 = *(const s8*)&s_gb[gbp][n * 72 + q * 8 + 32];
        f4 c[4];
#pragma unroll
        for (int T = 0; T < 4; ++T) {
            f4 z = __builtin_amdgcn_mfma_f32_16x16x32_bf16(a0, bfrag[T][0], b2i[T], 0, 0, 0);
            c[T] = __builtin_amdgcn_mfma_f32_16x16x32_bf16(a1, bfrag[T][1], z, 0, 0, 0);
        }
#pragma unroll
        for (int r = 0; r < 4; ++r)
#pragma unroll
            for (int T = 0; T < 4; ++T)
                accr[T] = fmaf(c[T][r], fvc[r][T], accr[T]);

        int gn = g0 + 16, bn = b;
        const bool endseg = (gn >= b);
        if (endseg) {
            gn = b;
            if (gn < te) bn = seg_end(m0, m1, gn);
            const int dcur = s_dst[g0];
#pragma unroll
            for (int T = 0; T < 4; ++T) {
                float v = accr[T];
                v += __shfl_xor(v, 16, 64);
                v += __shfl_xor(v, 32, 64);
                if (q == 0)
                    atomicAdd(&P.acc[(long)dcur * 128 + w * 64 + 4 * n + T], v);
            }
            f4 z = {0.f, 0.f, 0.f, 0.f};
            accr = z;
        }
        if (gn >= te) break;
        // reload fvc for next group (after last use; latency covered by next layer1)
#pragma unroll
        for (int r = 0; r < 4; ++r) {
            int row = gn + q * 4 + r;
            if (row < bn) fvc[r] = *(const f4*)&fyl[s_off[row]];
            else { f4 z = {0.f, 0.f, 0.f, 0.f}; fvc[r] = z; }
        }
        g0 = gn; b = bn;
        gbp ^= 1;
    }
}

// grid-stride float4 zero fill (n multiple of 4)
__global__ void zero_kernel(float* __restrict__ p, long n) {
    long i = ((long)blockIdx.x * 256 + threadIdx.x) * 4;
    if (i < n) { f4 z = {0.f, 0.f, 0.f, 0.f}; *(f4*)&p[i] = z; }
}

// epilogue for gno00+gno01 (contiguous acc buffers) + zero the gno10 acc
__global__ __launch_bounds__(256) void epi0001_kernel(
    float* __restrict__ acc, const int* __restrict__ rp00, int N0,
    const int* __restrict__ rp01, float* __restrict__ vd0zero, long ntot)
{
    long idx = (long)blockIdx.x * 256 + threadIdx.x;
    if (idx >= ntot) return;
    int d = (int)(idx >> 7);
    float deg;
    if (d < N0) { deg = (float)(rp00[d + 1] - rp00[d]); vd0zero[idx] = 0.f; }
    else        { deg = (float)(rp01[d - N0 + 1] - rp01[d - N0]); }
    acc[idx] = acc[idx] / fmaxf(deg, 1.f);
}

// fused: u = relu(accu/deg + w1t) (zero accu after read); vd1 = relu(base + u);
// w1t = vd1 @ W + bias. it0: accu=null -> vd1 = relu(base); zbuf zeroed.
__global__ __launch_bounds__(128) void relu_mm_kernel(
    const float* __restrict__ base, float* __restrict__ accu,
    const int* __restrict__ rowptr, float* __restrict__ w1t,
    const float* __restrict__ W, const float* __restrict__ bias,
    float* __restrict__ vout, float* __restrict__ zbuf, int R)
{
    const int r0 = blockIdx.x * 8;
    const int t = threadIdx.x;
    __shared__ float s_x[8 * 128];
#pragma unroll
    for (int j = 0; j < 8; ++j) {
        int r = r0 + j;
        long o = (long)r * 128 + t;
        float v = base[o];
        if (accu) {
            float deg = (float)(rowptr[r + 1] - rowptr[r]);
            float u = fmaxf(accu[o] / fmaxf(deg, 1.f) + w1t[o], 0.f);
            v += u;
            accu[o] = 0.f;
        } else if (zbuf) {
            zbuf[o] = 0.f;
        }
        v = fmaxf(v, 0.f);
        s_x[j * 128 + t] = v;
        vout[o] = v;
    }
    __syncthreads();
    float acc[8];
    const float bc = bias[t];
#pragma unroll
    for (int j = 0; j < 8; ++j) acc[j] = bc;
#pragma unroll 4
    for (int hh = 0; hh < 128; ++hh) {
        float wv = W[hh * 128 + t];
#pragma unroll
        for (int j = 0; j < 8; ++j) acc[j] += s_x[j * 128 + hh] * wv;
    }
#pragma unroll
    for (int j = 0; j < 8; ++j)
        w1t[(long)(r0 + j) * 128 + t] = acc[j];
}

// final gno11 epilogue (it2): v_up1 = relu(acc/deg + w1t), in place
__global__ __launch_bounds__(256) void epi11_kernel(
    float* __restrict__ acc, const int* __restrict__ rowptr,
    const float* __restrict__ w1t, int N)
{
    long idx = (long)blockIdx.x * 256 + threadIdx.x;
    if (idx >= (long)N * 128) return;
    int d = (int)(idx >> 7);
    float deg = (float)(rowptr[d + 1] - rowptr[d]);
    acc[idx] = fmaxf(acc[idx] / fmaxf(deg, 1.f) + w1t[idx], 0.f);
}

// fused lift + W0 matmul
__global__ __launch_bounds__(128) void lift_mm_kernel(
    const float* __restrict__ samples, const float* __restrict__ LW,
    const float* __restrict__ Lb, const float* __restrict__ W0,
    const float* __restrict__ W0b, float* __restrict__ vout,
    float* __restrict__ w0t, int R)
{
    const int r0 = blockIdx.x * 8;
    const int t = threadIdx.x;
    __shared__ float s_x[8 * 128];
#pragma unroll
    for (int j = 0; j < 8; ++j) {
        int r = r0 + j;
        float s0 = samples[r * 3 + 0], s1 = samples[r * 3 + 1], s2 = samples[r * 3 + 2];
        float v = s0 * LW[t] + s1 * LW[128 + t] + s2 * LW[256 + t] + Lb[t];
        s_x[j * 128 + t] = v;
        vout[(long)r * 128 + t] = v;
    }
    __syncthreads();
    float acc[8];
    const float bc = W0b[t];
#pragma unroll
    for (int j = 0; j < 8; ++j) acc[j] = bc;
#pragma unroll 4
    for (int hh = 0; hh < 128; ++hh) {
        float wv = W0[hh * 128 + t];
#pragma unroll
        for (int j = 0; j < 8; ++j) acc[j] += s_x[j * 128 + hh] * wv;
    }
#pragma unroll
    for (int j = 0; j < 8; ++j)
        w0t[(long)(r0 + j) * 128 + t] = acc[j];
}

// final epilogue + projection
__global__ __launch_bounds__(128) void epi_proj_kernel(
    const float* __restrict__ acc, const int* __restrict__ rowptr,
    const float* __restrict__ add0, const float* __restrict__ add1,
    const float* __restrict__ projw, const float* __restrict__ projb,
    float* __restrict__ fout, int N)
{
    const int d = blockIdx.x, t = threadIdx.x;
    float deg = (float)(rowptr[d + 1] - rowptr[d]);
    long o = (long)d * 128 + t;
    float res = fmaxf(acc[o] / fmaxf(deg, 1.f) + add0[o] + add1[o], 0.f);
    float p0 = res * projw[t * 3 + 0];
    float p1 = res * projw[t * 3 + 1];
    float p2 = res * projw[t * 3 + 2];
#pragma unroll
    for (int off = 32; off > 0; off >>= 1) {
        p0 += __shfl_down(p0, off);
        p1 += __shfl_down(p1, off);
        p2 += __shfl_down(p2, off);
    }
    __shared__ float sred[6];
    if ((t & 63) == 0) { int w = t >> 6; sred[w * 3 + 0] = p0; sred[w * 3 + 1] = p1; sred[w * 3 + 2] = p2; }
    __syncthreads();
    if (t < 3) fout[d * 3 + t] = sred[t] + sred[3 + t] + projb[t];
}

extern "C" void kernel_launch(void* const* d_in, const int* in_sizes, int n_in,
                              void* d_out, int out_size, void* d_ws, size_t ws_size,
                              hipStream_t stream)
{
    const float* coords  = (const float*)d_in[0];
    const float* samples = (const float*)d_in[1];
    const float* lift_w  = (const float*)d_in[3];
    const float* lift_b  = (const float*)d_in[4];
    const float* proj_w  = (const float*)d_in[5];
    const float* proj_b  = (const float*)d_in[6];
    const float* W0_w    = (const float*)d_in[7];
    const float* W0_b    = (const float*)d_in[8];
    const float* W1_w    = (const float*)d_in[9];
    const float* W1_b    = (const float*)d_in[10];
    const float *gw1[4], *gb1[4], *gw2[4], *gb2[4];   // 0=gk00,1=gk01,2=gk10,3=gk11
    for (int g = 0; g < 4; ++g) {
        gw1[g] = (const float*)d_in[11 + 4 * g + 0];
        gb1[g] = (const float*)d_in[11 + 4 * g + 1];
        gw2[g] = (const float*)d_in[11 + 4 * g + 2];
        gb2[g] = (const float*)d_in[11 + 4 * g + 3];
    }
    const int* es[4]; const int* ed[4]; int E[4];
    for (int g = 0; g < 4; ++g) {
        es[g] = (const int*)d_in[27 + 2 * g];
        ed[g] = (const int*)d_in[27 + 2 * g + 1];
        E[g]  = in_sizes[27 + 2 * g];
    }

    const int N0 = in_sizes[0] / 2;     // 8192
    const int N1 = (N0 + 1) / 2;        // 4096

    float* ws = (float*)d_ws;
    float* v_down0 = ws;                              // N0*128 (acc10 later)
    float* w0term  = v_down0 + (size_t)N0 * 128;      // N0*128
    float* gno00o  = w0term  + (size_t)N0 * 128;      // N0*128 (acc00)
    float* gno01b  = gno00o  + (size_t)N0 * 128;      // N1*128 (acc01, contiguous)
    float* v_down1 = gno01b  + (size_t)N1 * 128;      // N1*128
    float* w1term  = v_down1 + (size_t)N1 * 128;      // N1*128
    float* v_up1   = w1term  + (size_t)N1 * 128;      // N1*128 (acc11 in place)
    short* w2pack  = (short*)(v_up1 + (size_t)N1 * 128);  // 4*8192 bf16
    int*   rp      = (int*)(w2pack + 4 * 8192);
    int* rp00 = rp;                // N0+1
    int* rp01 = rp00 + (N0 + 1);   // N1+1
    int* rp10 = rp01 + (N1 + 1);   // N0+1
    int* rp11 = rp10 + (N0 + 1);   // N1+1

    {
        int maxE = E[0];
        for (int g = 1; g < 4; ++g) maxE = max(maxE, E[g]);
        RP a = {ed[0], E[0], N0, rp00};
        RP b = {ed[1], E[1], N1, rp01};
        RP c = {ed[2], E[2], N0, rp10};
        RP d = {ed[3], E[3], N1, rp11};
        dim3 grid((maxE + 255) / 256, 4);
        rowptr4_kernel<<<grid, 256, 0, stream>>>(a, b, c, d);
    }
    pack_w2_kernel<<<16, 128, 0, stream>>>(gw2[0], gw2[1], gw2[2], gw2[3], w2pack);

    const long n00 = (long)N0 * 128, n11 = (long)N1 * 128;

    zero_kernel<<<(int)((n00 + n11) / 4 + 255) / 256, 256, 0, stream>>>(gno00o, n00 + n11);
    lift_mm_kernel<<<N0 / 8, 128, 0, stream>>>(samples, lift_w, lift_b, W0_w, W0_b,
                                               v_down0, w0term, N0);

    GnoP P00 = {v_down0, es[0], ed[0], gw1[0], gb1[0], w2pack + 0 * 8192, gb2[0], gno00o, E[0], 1, 1, 0};
    GnoP P01 = {v_down0, es[1], ed[1], gw1[1], gb1[1], w2pack + 1 * 8192, gb2[1], gno01b, E[1], 2, 1, 0};
    GnoP P11 = {v_down1, es[3], ed[3], gw1[3], gb1[3], w2pack + 3 * 8192, gb2[3], v_up1,  E[3], 2, 2, 0};
    GnoP P10 = {v_up1,   es[2], ed[2], gw1[2], gb1[2], w2pack + 2 * 8192, gb2[2], v_down0, E[2], 1, 2, 0};

    {
        int tA = (E[0] + TILE - 1) / TILE, tB = (E[1] + TILE - 1) / TILE;
        gno_edge_kernel<<<tA + tB, 128, 0, stream>>>(coords, N0, P00, P01, tA);
    }
    epi0001_kernel<<<(int)((n00 + n11) + 255) / 256, 256, 0, stream>>>(
        gno00o, rp00, N0, rp01, v_down0, n00 + n11);

    for (int it = 0; it < 3; ++it) {
        relu_mm_kernel<<<N1 / 8, 128, 0, stream>>>(
            gno01b, (it == 0) ? nullptr : v_up1, rp11, w1term, W1_w, W1_b,
            v_down1, (it == 0) ? v_up1 : nullptr, N1);
        int tt = (E[3] + TILE - 1) / TILE;
        gno_edge_kernel<<<tt, 128, 0, stream>>>(coords, N0, P11, P11, tt);
    }
    epi11_kernel<<<(int)(n11 + 255) / 256, 256, 0, stream>>>(v_up1, rp11, w1term, N1);

    {
        int tt = (E[2] + TILE - 1) / TILE;
        gno_edge_kernel<<<tt, 128, 0, stream>>>(coords, N0, P10, P10, tt);
    }
    epi_proj_kernel<<<N0, 128, 0, stream>>>(v_down0, rp10, w0term, gno00o,
                                            proj_w, proj_b, (float*)d_out, N0);
}